// Round 16
// baseline (308.889 us; speedup 1.0000x reference)
//
#include <hip/hip_runtime.h>
#include <hip/hip_cooperative_groups.h>
#include <math.h>

namespace cg = cooperative_groups;

#define D_MODEL 64
#define D_STATE 16
#define D_INNER 128
#define DT_RANK 4
#define BB 8
#define LL 4096
#define NTOK (BB*LL)      // 32768
#define EPSV 1e-6f
#define NCHUNK 64
#define LC (LL/NCHUNK)    // 64
#define PAD 136           // bf16 LDS row stride (shorts), 16B-aligned rows

typedef __attribute__((ext_vector_type(8))) short bf16x8;
typedef __attribute__((ext_vector_type(4))) float f32x4;

__device__ __forceinline__ float sig_(float v) { return 1.f / (1.f + __expf(-v)); }
__device__ __forceinline__ float softplus_(float v) {
    return (v > 20.f) ? v : __logf(1.f + __expf(v));
}
__device__ __forceinline__ unsigned short f2bf(float x) {
    unsigned int u = __float_as_uint(x);
    u += 0x7fff + ((u >> 16) & 1);      // RNE
    return (unsigned short)(u >> 16);
}
__device__ __forceinline__ float bf2f(unsigned short u) {
    return __uint_as_float(((unsigned int)u) << 16);
}
__device__ __forceinline__ unsigned int pack2bf(float a, float b) {
    return (unsigned int)f2bf(a) | ((unsigned int)f2bf(b) << 16);
}

// Pack all weights to bf16 in one kernel.
__global__ __launch_bounds__(256) void pack_all(
    const float* __restrict__ W_in, const float* __restrict__ w_norm,
    const float* __restrict__ W_conv, const float* __restrict__ W_xp,
    const float* __restrict__ W_out,
    unsigned short* __restrict__ Win_bf, unsigned short* __restrict__ Bp,
    unsigned short* __restrict__ Wxp_bf, unsigned short* __restrict__ Wout_bf)
{
    int i = blockIdx.x * 256 + threadIdx.x;
    if (i < 16384) {
        Win_bf[i] = f2bf(W_in[i] * w_norm[i & 63]);
    } else if (i < 81920) {
        int j = i - 16384;
        int kk = j >> 14, o = (j >> 7) & 127, c = j & 127;
        Bp[j] = f2bf(W_conv[o * 512 + c * 4 + kk]);
    } else if (i < 88064) {
        int j = i - 81920;
        Wxp_bf[j] = ((j >> 7) < 36) ? f2bf(W_xp[j]) : (unsigned short)0;
    } else if (i < 96256) {
        int j = i - 88064;
        Wout_bf[j] = f2bf(W_out[j]);
    }
}

// ======================= Cooperative single-kernel path =======================
__global__ __launch_bounds__(256) void mamba_coop(
    const float* __restrict__ x, const unsigned short* __restrict__ Win_bf,
    const float* __restrict__ b_in,
    const unsigned short* __restrict__ Bp, const float* __restrict__ b_conv,
    const unsigned short* __restrict__ Wxp_bf, const float* __restrict__ b_xp,
    const float* __restrict__ W_dt, const float* __restrict__ b_dt,
    const float* __restrict__ A_log, const float* __restrict__ D_param,
    const unsigned short* __restrict__ Wout_bf, const float* __restrict__ b_out,
    unsigned short* __restrict__ z_bf,
    float* __restrict__ P, float* __restrict__ Q, float* __restrict__ Hinit,
    float* __restrict__ out)
{
    __shared__ unsigned char smem[64816];
    unsigned short* uls  = (unsigned short*)smem;             // [64][136] u_conv
    unsigned short* dlsu = (unsigned short*)(smem + 17408);   // [67][136] upre -> delta
    float* bls = (float*)(smem + 35632);                      // [64][16] Bm
    float* cls = (float*)(smem + 39728);                      // [64][16] Cm
    unsigned short* yzls = (unsigned short*)(smem + 43824);   // [64][136] z->y (late)
    unsigned short* axs  = yzls;                              // [80][72] normed x (early)
    float (*dts)[4] = (float(*)[4])(smem + 61232);            // [64][4]
    float* Wd  = (float*)(smem + 62256);                      // [512]
    float* bds = (float*)(smem + 64304);                      // [128]

    cg::grid_group grid = cg::this_grid();
    int tid = threadIdx.x;
    if (tid < 128) *(float4*)&Wd[tid * 4] = *(const float4*)&W_dt[tid * 4];
    else if (tid < 160) *(float4*)&bds[(tid - 128) * 4] = *(const float4*)&b_dt[(tid - 128) * 4];
    int wave = tid >> 6, lane = tid & 63;
    int quad = lane >> 4, l16 = lane & 15;
    int bid = blockIdx.x;
    int tb = bid * 64;
    int bbase = tb & ~4095;

    #pragma unroll
    for (int p = 0; p < 2; ++p) {
        int lrow = p * 64 + (tid >> 2);
        if (lrow < 67) {
            int qt = tid & 3;
            int g = tb - 3 + lrow;
            float4 v[4];
            float ss = 0.f;
            if (g >= bbase) {
                #pragma unroll
                for (int j = 0; j < 4; ++j) {
                    v[j] = *(const float4*)&x[g * 64 + qt * 16 + j * 4];
                    ss += v[j].x*v[j].x + v[j].y*v[j].y + v[j].z*v[j].z + v[j].w*v[j].w;
                }
            } else {
                #pragma unroll
                for (int j = 0; j < 4; ++j) v[j] = (float4){0.f, 0.f, 0.f, 0.f};
            }
            ss += __shfl_xor(ss, 1, 64);
            ss += __shfl_xor(ss, 2, 64);
            float r = rsqrtf(ss * (1.f / 64.f) + EPSV);
            unsigned short tmp[16];
            #pragma unroll
            for (int j = 0; j < 4; ++j) {
                tmp[4*j+0] = f2bf(v[j].x * r); tmp[4*j+1] = f2bf(v[j].y * r);
                tmp[4*j+2] = f2bf(v[j].z * r); tmp[4*j+3] = f2bf(v[j].w * r);
            }
            *(bf16x8*)&axs[lrow * 72 + qt * 16]     = *(bf16x8*)&tmp[0];
            *(bf16x8*)&axs[lrow * 72 + qt * 16 + 8] = *(bf16x8*)&tmp[8];
        }
    }
    __syncthreads();
    #pragma unroll
    for (int mt = 0; mt < 5; ++mt) {
        bf16x8 a0 = *(const bf16x8*)&axs[(mt * 16 + l16) * 72 + quad * 8];
        bf16x8 a1 = *(const bf16x8*)&axs[(mt * 16 + l16) * 72 + 32 + quad * 8];
        f32x4 acc[4];
        #pragma unroll
        for (int nk = 0; nk < 4; ++nk) acc[nk] = (f32x4){0.f, 0.f, 0.f, 0.f};
        #pragma unroll
        for (int nk = 0; nk < 4; ++nk) {
            int nt = wave * 4 + nk;
            bf16x8 b0 = *(const bf16x8*)&Win_bf[(nt * 16 + l16) * 64 + quad * 8];
            bf16x8 b1 = *(const bf16x8*)&Win_bf[(nt * 16 + l16) * 64 + 32 + quad * 8];
            acc[nk] = __builtin_amdgcn_mfma_f32_16x16x32_bf16(a0, b0, acc[nk], 0, 0, 0);
            acc[nk] = __builtin_amdgcn_mfma_f32_16x16x32_bf16(a1, b1, acc[nk], 0, 0, 0);
        }
        #pragma unroll
        for (int nk = 0; nk < 4; ++nk) {
            int o = (wave * 4 + nk) * 16 + l16;
            float bo = b_in[o];
            #pragma unroll
            for (int r = 0; r < 4; ++r) {
                int lrow = mt * 16 + quad * 4 + r;
                if (lrow < 67) {
                    float v = acc[nk][r] + bo;
                    if (o < 128) {
                        dlsu[lrow * PAD + o] = f2bf(v);
                    } else if (lrow >= 3) {
                        float zv = v * sig_(v);
                        z_bf[(tb + lrow - 3) * 128 + (o - 128)] = f2bf(zv);
                    }
                }
            }
        }
    }
    __syncthreads();
    {
        f32x4 acc[8];
        #pragma unroll
        for (int og = 0; og < 8; ++og) acc[og] = (f32x4){0.f, 0.f, 0.f, 0.f};
        #pragma unroll
        for (int kk = 0; kk < 4; ++kk) {
            int lr = wave * 16 + l16 + kk;
            #pragma unroll
            for (int cs = 0; cs < 4; ++cs) {
                int kbase = cs * 32 + quad * 8;
                bf16x8 a = *(const bf16x8*)&dlsu[lr * PAD + kbase];
                #pragma unroll
                for (int og = 0; og < 8; ++og) {
                    bf16x8 b = *(const bf16x8*)&Bp[kk * 16384 + (og * 16 + l16) * 128 + kbase];
                    acc[og] = __builtin_amdgcn_mfma_f32_16x16x32_bf16(a, b, acc[og], 0, 0, 0);
                }
            }
        }
        __syncthreads();
        #pragma unroll
        for (int og = 0; og < 8; ++og) {
            int o = og * 16 + l16;
            float bc = b_conv[o];
            #pragma unroll
            for (int r = 0; r < 4; ++r) {
                int tloc = wave * 16 + quad * 4 + r;
                float v = acc[og][r] + bc;
                uls[tloc * PAD + o] = f2bf(v * sig_(v));
            }
        }
    }
    __syncthreads();
    {
        f32x4 xacc[3];
        #pragma unroll
        for (int nt = 0; nt < 3; ++nt) xacc[nt] = (f32x4){0.f, 0.f, 0.f, 0.f};
        #pragma unroll
        for (int cs = 0; cs < 4; ++cs) {
            int kbase = cs * 32 + quad * 8;
            bf16x8 a = *(const bf16x8*)&uls[(wave * 16 + l16) * PAD + kbase];
            #pragma unroll
            for (int nt = 0; nt < 3; ++nt) {
                bf16x8 b = *(const bf16x8*)&Wxp_bf[(nt * 16 + l16) * 128 + kbase];
                xacc[nt] = __builtin_amdgcn_mfma_f32_16x16x32_bf16(a, b, xacc[nt], 0, 0, 0);
            }
        }
        #pragma unroll
        for (int nt = 0; nt < 3; ++nt) {
            int j = nt * 16 + l16;
            float bx = (j < 36) ? b_xp[j] : 0.f;
            #pragma unroll
            for (int r = 0; r < 4; ++r) {
                int tloc = wave * 16 + quad * 4 + r;
                float val = xacc[nt][r] + bx;
                if (j < 4)       dts[tloc][j] = val;
                else if (j < 20) bls[tloc * 16 + (j - 4)]  = val;
                else if (j < 36) cls[tloc * 16 + (j - 20)] = val;
            }
        }
    }
    __syncthreads();
    {
        int tokloc = tid >> 2, dgrp = tid & 3;
        float dt0 = dts[tokloc][0], dt1 = dts[tokloc][1],
              dt2 = dts[tokloc][2], dt3 = dts[tokloc][3];
        #pragma unroll
        for (int d4 = 0; d4 < 8; ++d4) {
            int d = dgrp * 32 + d4 * 4;
            float4 w0 = *(const float4*)&Wd[(d + 0) * 4];
            float4 w1 = *(const float4*)&Wd[(d + 1) * 4];
            float4 w2 = *(const float4*)&Wd[(d + 2) * 4];
            float4 w3 = *(const float4*)&Wd[(d + 3) * 4];
            float4 bdv = *(const float4*)&bds[d];
            float4 r;
            r.x = softplus_(bdv.x + dt0*w0.x + dt1*w0.y + dt2*w0.z + dt3*w0.w);
            r.y = softplus_(bdv.y + dt0*w1.x + dt1*w1.y + dt2*w1.z + dt3*w1.w);
            r.z = softplus_(bdv.z + dt0*w2.x + dt1*w2.y + dt2*w2.z + dt3*w2.w);
            r.w = softplus_(bdv.w + dt0*w3.x + dt1*w3.y + dt2*w3.z + dt3*w3.w);
            uint2 pk; pk.x = pack2bf(r.x, r.y); pk.y = pack2bf(r.z, r.w);
            *(uint2*)&dlsu[tokloc * PAD + d] = pk;
        }
    }
    __syncthreads();
    {
        int d = tid >> 1;
        int nb = (tid & 1) * 8;
        float4 Av0 = *(const float4*)&A_log[d * 16 + nb];
        float4 Av1 = *(const float4*)&A_log[d * 16 + nb + 4];
        float A0 = -__expf(Av0.x), A1 = -__expf(Av0.y),
              A2 = -__expf(Av0.z), A3 = -__expf(Av0.w);
        float A4 = -__expf(Av1.x), A5 = -__expf(Av1.y),
              A6 = -__expf(Av1.z), A7 = -__expf(Av1.w);
        float P0=1.f,P1=1.f,P2=1.f,P3=1.f,P4=1.f,P5=1.f,P6=1.f,P7=1.f;
        float Q0=0.f,Q1=0.f,Q2=0.f,Q3=0.f,Q4=0.f,Q5=0.f,Q6=0.f,Q7=0.f;
        for (int t = 0; t < LC; ++t) {
            float dl = bf2f(dlsu[t * PAD + d]);
            float uu = bf2f(uls[t * PAD + d]);
            float4 bm0 = *(const float4*)&bls[t * 16 + nb];
            float4 bm1 = *(const float4*)&bls[t * 16 + nb + 4];
            float du = dl * uu;
            float a0 = __expf(dl * A0), a1 = __expf(dl * A1),
                  a2 = __expf(dl * A2), a3 = __expf(dl * A3);
            float a4 = __expf(dl * A4), a5 = __expf(dl * A5),
                  a6 = __expf(dl * A6), a7 = __expf(dl * A7);
            P0 *= a0; P1 *= a1; P2 *= a2; P3 *= a3;
            P4 *= a4; P5 *= a5; P6 *= a6; P7 *= a7;
            Q0 = a0 * Q0 + du * bm0.x; Q1 = a1 * Q1 + du * bm0.y;
            Q2 = a2 * Q2 + du * bm0.z; Q3 = a3 * Q3 + du * bm0.w;
            Q4 = a4 * Q4 + du * bm1.x; Q5 = a5 * Q5 + du * bm1.y;
            Q6 = a6 * Q6 + du * bm1.z; Q7 = a7 * Q7 + du * bm1.w;
        }
        int idx = bid * 2048 + d * 16 + nb;
        *(float4*)&P[idx]     = (float4){P0, P1, P2, P3};
        *(float4*)&P[idx + 4] = (float4){P4, P5, P6, P7};
        *(float4*)&Q[idx]     = (float4){Q0, Q1, Q2, Q3};
        *(float4*)&Q[idx + 4] = (float4){Q4, Q5, Q6, Q7};
    }
    grid.sync();
    if (bid < 64) {
        int b = bid >> 3;
        int dn = (bid & 7) * 256 + tid;
        float carry = 0.f;
        for (int c0 = 0; c0 < NCHUNK; c0 += 8) {
            float p[8], q[8];
            #pragma unroll
            for (int j = 0; j < 8; ++j) {
                int idx = (b * NCHUNK + c0 + j) * 2048 + dn;
                p[j] = P[idx]; q[j] = Q[idx];
            }
            #pragma unroll
            for (int j = 0; j < 8; ++j) {
                int idx = (b * NCHUNK + c0 + j) * 2048 + dn;
                Hinit[idx] = carry;
                carry = p[j] * carry + q[j];
            }
        }
    }
    grid.sync();
    for (int i = tid; i < LC * 16; i += 256) {
        int row = i >> 4, q = i & 15;
        *(float4*)&yzls[row * PAD + q * 8] =
            *(const float4*)&z_bf[(tb + row) * 128 + q * 8];
    }
    int d = tid >> 1;
    int nb = (tid & 1) * 8;
    float4 Av0 = *(const float4*)&A_log[d * 16 + nb];
    float4 Av1 = *(const float4*)&A_log[d * 16 + nb + 4];
    float A0 = -__expf(Av0.x), A1 = -__expf(Av0.y), A2 = -__expf(Av0.z), A3 = -__expf(Av0.w);
    float A4 = -__expf(Av1.x), A5 = -__expf(Av1.y), A6 = -__expf(Av1.z), A7 = -__expf(Av1.w);
    int hbase = bid * 2048 + d * 16 + nb;
    float4 h0 = *(const float4*)&Hinit[hbase];
    float4 h1 = *(const float4*)&Hinit[hbase + 4];
    float Dp = D_param[d];
    __syncthreads();
    for (int t = 0; t < LC; ++t) {
        float dl = bf2f(dlsu[t * PAD + d]);
        float uu = bf2f(uls[t * PAD + d]);
        float4 bm0 = *(const float4*)&bls[t * 16 + nb];
        float4 bm1 = *(const float4*)&bls[t * 16 + nb + 4];
        float4 cm0 = *(const float4*)&cls[t * 16 + nb];
        float4 cm1 = *(const float4*)&cls[t * 16 + nb + 4];
        float du = dl * uu;
        float a0 = __expf(dl * A0), a1 = __expf(dl * A1),
              a2 = __expf(dl * A2), a3 = __expf(dl * A3);
        float a4 = __expf(dl * A4), a5 = __expf(dl * A5),
              a6 = __expf(dl * A6), a7 = __expf(dl * A7);
        h0.x = a0 * h0.x + du * bm0.x; h0.y = a1 * h0.y + du * bm0.y;
        h0.z = a2 * h0.z + du * bm0.z; h0.w = a3 * h0.w + du * bm0.w;
        h1.x = a4 * h1.x + du * bm1.x; h1.y = a5 * h1.y + du * bm1.y;
        h1.z = a6 * h1.z + du * bm1.z; h1.w = a7 * h1.w + du * bm1.w;
        float yv = h0.x * cm0.x + h0.y * cm0.y + h0.z * cm0.z + h0.w * cm0.w
                 + h1.x * cm1.x + h1.y * cm1.y + h1.z * cm1.z + h1.w * cm1.w;
        yv += __shfl_xor(yv, 1, 64);
        if ((tid & 1) == 0) {
            float y = yv + Dp * uu;
            y *= bf2f(yzls[t * PAD + d]);
            yzls[t * PAD + d] = f2bf(y);
        }
    }
    __syncthreads();
    {
        f32x4 oacc[4];
        #pragma unroll
        for (int nt = 0; nt < 4; ++nt) oacc[nt] = (f32x4){0.f, 0.f, 0.f, 0.f};
        #pragma unroll
        for (int cs = 0; cs < 4; ++cs) {
            int kbase = cs * 32 + quad * 8;
            bf16x8 a = *(const bf16x8*)&yzls[(wave * 16 + l16) * PAD + kbase];
            #pragma unroll
            for (int nt = 0; nt < 4; ++nt) {
                bf16x8 bb = *(const bf16x8*)&Wout_bf[(nt * 16 + l16) * 128 + kbase];
                oacc[nt] = __builtin_amdgcn_mfma_f32_16x16x32_bf16(a, bb, oacc[nt], 0, 0, 0);
            }
        }
        #pragma unroll
        for (int nt = 0; nt < 4; ++nt) {
            int m = nt * 16 + l16;
            float bo = b_out[m];
            #pragma unroll
            for (int r = 0; r < 4; ++r) {
                int t = tb + wave * 16 + quad * 4 + r;
                out[t * 64 + m] = oacc[nt][r] + bo + x[t * 64 + m];
            }
        }
    }
}

// ======================= R14 fallback path (proven) =======================
__global__ __launch_bounds__(256) void k123a_fused(
    const float* __restrict__ x, const unsigned short* __restrict__ Win_bf,
    const float* __restrict__ b_in,
    const unsigned short* __restrict__ Bp, const float* __restrict__ b_conv,
    const unsigned short* __restrict__ Wxp_bf, const float* __restrict__ b_xp,
    const float* __restrict__ W_dt, const float* __restrict__ b_dt,
    const float* __restrict__ A_log,
    unsigned short* __restrict__ z_bf, unsigned short* __restrict__ u_cbf,
    unsigned short* __restrict__ delta_bf,
    float* __restrict__ Bm, float* __restrict__ Cm,
    float* __restrict__ P, float* __restrict__ Q)
{
    __shared__ unsigned char smem[54832];
    unsigned short* axs  = (unsigned short*)smem;
    unsigned short* upre = (unsigned short*)(smem + 11520);
    unsigned short* dls  = upre;
    unsigned short* uls  = (unsigned short*)(smem + 29744);
    float* bls = (float*)(smem + 47152);
    float (*dts)[4] = (float(*)[4])(smem + 51248);
    float* Wd  = (float*)(smem + 52272);
    float* bds = (float*)(smem + 54320);

    int tid = threadIdx.x;
    if (tid < 128) *(float4*)&Wd[tid * 4] = *(const float4*)&W_dt[tid * 4];
    else if (tid < 160) *(float4*)&bds[(tid - 128) * 4] = *(const float4*)&b_dt[(tid - 128) * 4];
    int wave = tid >> 6, lane = tid & 63;
    int quad = lane >> 4, l16 = lane & 15;
    int tb = blockIdx.x * 64;
    int bbase = tb & ~4095;

    #pragma unroll
    for (int p = 0; p < 2; ++p) {
        int lrow = p * 64 + (tid >> 2);
        if (lrow < 67) {
            int qt = tid & 3;
            int g = tb - 3 + lrow;
            float4 v[4];
            float ss = 0.f;
            if (g >= bbase) {
                #pragma unroll
                for (int j = 0; j < 4; ++j) {
                    v[j] = *(const float4*)&x[g * 64 + qt * 16 + j * 4];
                    ss += v[j].x*v[j].x + v[j].y*v[j].y + v[j].z*v[j].z + v[j].w*v[j].w;
                }
            } else {
                #pragma unroll
                for (int j = 0; j < 4; ++j) v[j] = (float4){0.f, 0.f, 0.f, 0.f};
            }
            ss += __shfl_xor(ss, 1, 64);
            ss += __shfl_xor(ss, 2, 64);
            float r = rsqrtf(ss * (1.f / 64.f) + EPSV);
            unsigned short tmp[16];
            #pragma unroll
            for (int j = 0; j < 4; ++j) {
                tmp[4*j+0] = f2bf(v[j].x * r); tmp[4*j+1] = f2bf(v[j].y * r);
                tmp[4*j+2] = f2bf(v[j].z * r); tmp[4*j+3] = f2bf(v[j].w * r);
            }
            *(bf16x8*)&axs[lrow * 72 + qt * 16]     = *(bf16x8*)&tmp[0];
            *(bf16x8*)&axs[lrow * 72 + qt * 16 + 8] = *(bf16x8*)&tmp[8];
        }
    }
    __syncthreads();
    #pragma unroll
    for (int mt = 0; mt < 5; ++mt) {
        bf16x8 a0 = *(const bf16x8*)&axs[(mt * 16 + l16) * 72 + quad * 8];
        bf16x8 a1 = *(const bf16x8*)&axs[(mt * 16 + l16) * 72 + 32 + quad * 8];
        f32x4 acc[4];
        #pragma unroll
        for (int nk = 0; nk < 4; ++nk) acc[nk] = (f32x4){0.f, 0.f, 0.f, 0.f};
        #pragma unroll
        for (int nk = 0; nk < 4; ++nk) {
            int nt = wave * 4 + nk;
            bf16x8 b0 = *(const bf16x8*)&Win_bf[(nt * 16 + l16) * 64 + quad * 8];
            bf16x8 b1 = *(const bf16x8*)&Win_bf[(nt * 16 + l16) * 64 + 32 + quad * 8];
            acc[nk] = __builtin_amdgcn_mfma_f32_16x16x32_bf16(a0, b0, acc[nk], 0, 0, 0);
            acc[nk] = __builtin_amdgcn_mfma_f32_16x16x32_bf16(a1, b1, acc[nk], 0, 0, 0);
        }
        #pragma unroll
        for (int nk = 0; nk < 4; ++nk) {
            int o = (wave * 4 + nk) * 16 + l16;
            float bo = b_in[o];
            #pragma unroll
            for (int r = 0; r < 4; ++r) {
                int lrow = mt * 16 + quad * 4 + r;
                if (lrow < 67) {
                    float v = acc[nk][r] + bo;
                    if (o < 128) {
                        upre[lrow * PAD + o] = f2bf(v);
                    } else if (lrow >= 3) {
                        float zv = v * sig_(v);
                        z_bf[(tb + lrow - 3) * 128 + (o - 128)] = f2bf(zv);
                    }
                }
            }
        }
    }
    __syncthreads();
    {
        f32x4 acc[8];
        #pragma unroll
        for (int og = 0; og < 8; ++og) acc[og] = (f32x4){0.f, 0.f, 0.f, 0.f};
        #pragma unroll
        for (int kk = 0; kk < 4; ++kk) {
            int lr = wave * 16 + l16 + kk;
            #pragma unroll
            for (int cs = 0; cs < 4; ++cs) {
                int kbase = cs * 32 + quad * 8;
                bf16x8 a = *(const bf16x8*)&upre[lr * PAD + kbase];
                #pragma unroll
                for (int og = 0; og < 8; ++og) {
                    bf16x8 b = *(const bf16x8*)&Bp[kk * 16384 + (og * 16 + l16) * 128 + kbase];
                    acc[og] = __builtin_amdgcn_mfma_f32_16x16x32_bf16(a, b, acc[og], 0, 0, 0);
                }
            }
        }
        #pragma unroll
        for (int og = 0; og < 8; ++og) {
            int o = og * 16 + l16;
            float bc = b_conv[o];
            #pragma unroll
            for (int r = 0; r < 4; ++r) {
                int tloc = wave * 16 + quad * 4 + r;
                float v = acc[og][r] + bc;
                unsigned short ub = f2bf(v * sig_(v));
                u_cbf[(tb + tloc) * 128 + o] = ub;
                uls[tloc * PAD + o] = ub;
            }
        }
    }
    __syncthreads();
    {
        f32x4 xacc[3];
        #pragma unroll
        for (int nt = 0; nt < 3; ++nt) xacc[nt] = (f32x4){0.f, 0.f, 0.f, 0.f};
        #pragma unroll
        for (int cs = 0; cs < 4; ++cs) {
            int kbase = cs * 32 + quad * 8;
            bf16x8 a = *(const bf16x8*)&uls[(wave * 16 + l16) * PAD + kbase];
            #pragma unroll
            for (int nt = 0; nt < 3; ++nt) {
                bf16x8 b = *(const bf16x8*)&Wxp_bf[(nt * 16 + l16) * 128 + kbase];
                xacc[nt] = __builtin_amdgcn_mfma_f32_16x16x32_bf16(a, b, xacc[nt], 0, 0, 0);
            }
        }
        #pragma unroll
        for (int nt = 0; nt < 3; ++nt) {
            int j = nt * 16 + l16;
            float bx = (j < 36) ? b_xp[j] : 0.f;
            #pragma unroll
            for (int r = 0; r < 4; ++r) {
                int tloc = wave * 16 + quad * 4 + r;
                int t = tb + tloc;
                float val = xacc[nt][r] + bx;
                if (j < 4) {
                    dts[tloc][j] = val;
                } else if (j < 20) {
                    Bm[t * 16 + (j - 4)] = val;
                    bls[tloc * 16 + (j - 4)] = val;
                } else if (j < 36) {
                    Cm[t * 16 + (j - 20)] = val;
                }
            }
        }
    }
    __syncthreads();
    {
        int tokloc = tid >> 2, dgrp = tid & 3;
        float dt0 = dts[tokloc][0], dt1 = dts[tokloc][1],
              dt2 = dts[tokloc][2], dt3 = dts[tokloc][3];
        int g = tb + tokloc;
        #pragma unroll
        for (int d4 = 0; d4 < 8; ++d4) {
            int d = dgrp * 32 + d4 * 4;
            float4 w0 = *(const float4*)&Wd[(d + 0) * 4];
            float4 w1 = *(const float4*)&Wd[(d + 1) * 4];
            float4 w2 = *(const float4*)&Wd[(d + 2) * 4];
            float4 w3 = *(const float4*)&Wd[(d + 3) * 4];
            float4 bdv = *(const float4*)&bds[d];
            float4 r;
            r.x = softplus_(bdv.x + dt0*w0.x + dt1*w0.y + dt2*w0.z + dt3*w0.w);
            r.y = softplus_(bdv.y + dt0*w1.x + dt1*w1.y + dt2*w1.z + dt3*w1.w);
            r.z = softplus_(bdv.z + dt0*w2.x + dt1*w2.y + dt2*w2.z + dt3*w2.w);
            r.w = softplus_(bdv.w + dt0*w3.x + dt1*w3.y + dt2*w3.z + dt3*w3.w);
            uint2 pk; pk.x = pack2bf(r.x, r.y); pk.y = pack2bf(r.z, r.w);
            *(uint2*)&delta_bf[g * 128 + d] = pk;
            *(uint2*)&dls[tokloc * PAD + d] = pk;
        }
    }
    __syncthreads();
    {
        int d = tid >> 1;
        int nb = (tid & 1) * 8;
        float4 Av0 = *(const float4*)&A_log[d * 16 + nb];
        float4 Av1 = *(const float4*)&A_log[d * 16 + nb + 4];
        float A0 = -__expf(Av0.x), A1 = -__expf(Av0.y),
              A2 = -__expf(Av0.z), A3 = -__expf(Av0.w);
        float A4 = -__expf(Av1.x), A5 = -__expf(Av1.y),
              A6 = -__expf(Av1.z), A7 = -__expf(Av1.w);
        float P0=1.f,P1=1.f,P2=1.f,P3=1.f,P4=1.f,P5=1.f,P6=1.f,P7=1.f;
        float Q0=0.f,Q1=0.f,Q2=0.f,Q3=0.f,Q4=0.f,Q5=0.f,Q6=0.f,Q7=0.f;
        for (int t = 0; t < LC; ++t) {
            float dl = bf2f(dls[t * PAD + d]);
            float uu = bf2f(uls[t * PAD + d]);
            float4 bm0 = *(const float4*)&bls[t * 16 + nb];
            float4 bm1 = *(const float4*)&bls[t * 16 + nb + 4];
            float du = dl * uu;
            float a0 = __expf(dl * A0), a1 = __expf(dl * A1),
                  a2 = __expf(dl * A2), a3 = __expf(dl * A3);
            float a4 = __expf(dl * A4), a5 = __expf(dl * A5),
                  a6 = __expf(dl * A6), a7 = __expf(dl * A7);
            P0 *= a0; P1 *= a1; P2 *= a2; P3 *= a3;
            P4 *= a4; P5 *= a5; P6 *= a6; P7 *= a7;
            Q0 = a0 * Q0 + du * bm0.x; Q1 = a1 * Q1 + du * bm0.y;
            Q2 = a2 * Q2 + du * bm0.z; Q3 = a3 * Q3 + du * bm0.w;
            Q4 = a4 * Q4 + du * bm1.x; Q5 = a5 * Q5 + du * bm1.y;
            Q6 = a6 * Q6 + du * bm1.z; Q7 = a7 * Q7 + du * bm1.w;
        }
        int idx = blockIdx.x * 2048 + d * 16 + nb;
        *(float4*)&P[idx]     = (float4){P0, P1, P2, P3};
        *(float4*)&P[idx + 4] = (float4){P4, P5, P6, P7};
        *(float4*)&Q[idx]     = (float4){Q0, Q1, Q2, Q3};
        *(float4*)&Q[idx + 4] = (float4){Q4, Q5, Q6, Q7};
    }
}

__global__ __launch_bounds__(256) void k4b_carry(
    const float* __restrict__ P, const float* __restrict__ Q, float* __restrict__ Hinit)
{
    int tid = blockIdx.x * 256 + threadIdx.x;
    int b = tid >> 11, dn = tid & 2047;
    float carry = 0.f;
    for (int c0 = 0; c0 < NCHUNK; c0 += 8) {
        float p[8], q[8];
        #pragma unroll
        for (int j = 0; j < 8; ++j) {
            int idx = (b * NCHUNK + c0 + j) * 2048 + dn;
            p[j] = P[idx]; q[j] = Q[idx];
        }
        #pragma unroll
        for (int j = 0; j < 8; ++j) {
            int idx = (b * NCHUNK + c0 + j) * 2048 + dn;
            Hinit[idx] = carry;
            carry = p[j] * carry + q[j];
        }
    }
}

__global__ __launch_bounds__(256) void k4c5_fused(
    const unsigned short* __restrict__ delta_bf, const unsigned short* __restrict__ u_cbf,
    const float* __restrict__ Bm, const float* __restrict__ Cm,
    const unsigned short* __restrict__ z_bf, const float* __restrict__ A_log,
    const float* __restrict__ D_param, const float* __restrict__ Hinit,
    const unsigned short* __restrict__ Wout_bf, const float* __restrict__ b_out,
    const float* __restrict__ x, float* __restrict__ out)
{
    __shared__ unsigned short dls[LC * 128];
    __shared__ unsigned short uls[LC * 128];
    __shared__ float bls[LC * 16];
    __shared__ float cls[LC * 16];
    __shared__ unsigned short yzls[LC * PAD];
    int bid = blockIdx.x;
    int tid = threadIdx.x, lane = tid & 63;
    int g0 = bid * 64;
    for (int i = tid; i < LC * 16; i += 256) {
        int row = i >> 4, q = i & 15;
        *(float4*)&dls[row * 128 + q * 8] =
            *(const float4*)&delta_bf[(g0 + row) * 128 + q * 8];
        *(float4*)&uls[row * 128 + q * 8] =
            *(const float4*)&u_cbf[(g0 + row) * 128 + q * 8];
        *(float4*)&yzls[row * PAD + q * 8] =
            *(const float4*)&z_bf[(g0 + row) * 128 + q * 8];
    }
    for (int i = tid; i < LC * 4; i += 256) {
        int row = i >> 2, q = i & 3;
        *(float4*)&bls[row * 16 + q * 4] = *(const float4*)&Bm[(g0 + row) * 16 + q * 4];
        *(float4*)&cls[row * 16 + q * 4] = *(const float4*)&Cm[(g0 + row) * 16 + q * 4];
    }
    int d = tid >> 1;
    int nb = (tid & 1) * 8;
    float4 Av0 = *(const float4*)&A_log[d * 16 + nb];
    float4 Av1 = *(const float4*)&A_log[d * 16 + nb + 4];
    float A0 = -__expf(Av0.x), A1 = -__expf(Av0.y), A2 = -__expf(Av0.z), A3 = -__expf(Av0.w);
    float A4 = -__expf(Av1.x), A5 = -__expf(Av1.y), A6 = -__expf(Av1.z), A7 = -__expf(Av1.w);
    int hbase = bid * 2048 + d * 16 + nb;
    float4 h0 = *(const float4*)&Hinit[hbase];
    float4 h1 = *(const float4*)&Hinit[hbase + 4];
    float Dp = D_param[d];
    __syncthreads();
    for (int t = 0; t < LC; ++t) {
        float dl = bf2f(dls[t * 128 + d]);
        float uu = bf2f(uls[t * 128 + d]);
        float4 bm0 = *(const float4*)&bls[t * 16 + nb];
        float4 bm1 = *(const float4*)&bls[t * 16 + nb + 4];
        float4 cm0 = *(const float4*)&cls[t * 16 + nb];
        float4 cm1 = *(const float4*)&cls[t * 16 + nb + 4];
        float du = dl * uu;
        float a0 = __expf(dl * A0), a1 = __expf(dl * A1),
              a2 = __expf(dl * A2), a3 = __expf(dl * A3);
        float a4 = __expf(dl * A4), a5 = __expf(dl * A5),
              a6 = __expf(dl * A6), a7 = __expf(dl * A7);
        h0.x = a0 * h0.x + du * bm0.x; h0.y = a1 * h0.y + du * bm0.y;
        h0.z = a2 * h0.z + du * bm0.z; h0.w = a3 * h0.w + du * bm0.w;
        h1.x = a4 * h1.x + du * bm1.x; h1.y = a5 * h1.y + du * bm1.y;
        h1.z = a6 * h1.z + du * bm1.z; h1.w = a7 * h1.w + du * bm1.w;
        float yv = h0.x * cm0.x + h0.y * cm0.y + h0.z * cm0.z + h0.w * cm0.w
                 + h1.x * cm1.x + h1.y * cm1.y + h1.z * cm1.z + h1.w * cm1.w;
        yv += __shfl_xor(yv, 1, 64);
        if ((tid & 1) == 0) {
            float y = yv + Dp * uu;
            y *= bf2f(yzls[t * PAD + d]);
            yzls[t * PAD + d] = f2bf(y);
        }
    }
    __syncthreads();
    int wave = tid >> 6;
    int quad = lane >> 4, l16 = lane & 15;
    f32x4 oacc[4];
    #pragma unroll
    for (int nt = 0; nt < 4; ++nt) oacc[nt] = (f32x4){0.f, 0.f, 0.f, 0.f};
    #pragma unroll
    for (int cs = 0; cs < 4; ++cs) {
        int kbase = cs * 32 + quad * 8;
        bf16x8 a = *(const bf16x8*)&yzls[(wave * 16 + l16) * PAD + kbase];
        #pragma unroll
        for (int nt = 0; nt < 4; ++nt) {
            bf16x8 bb = *(const bf16x8*)&Wout_bf[(nt * 16 + l16) * 128 + kbase];
            oacc[nt] = __builtin_amdgcn_mfma_f32_16x16x32_bf16(a, bb, oacc[nt], 0, 0, 0);
        }
    }
    #pragma unroll
    for (int nt = 0; nt < 4; ++nt) {
        int m = nt * 16 + l16;
        float bo = b_out[m];
        #pragma unroll
        for (int r = 0; r < 4; ++r) {
            int t = g0 + wave * 16 + quad * 4 + r;
            out[t * 64 + m] = oacc[nt][r] + bo + x[t * 64 + m];
        }
    }
}

extern "C" void kernel_launch(void* const* d_in, const int* in_sizes, int n_in,
                              void* d_out, int out_size, void* d_ws, size_t ws_size,
                              hipStream_t stream)
{
    const float* x       = (const float*)d_in[0];
    const float* w_norm  = (const float*)d_in[1];
    const float* W_in    = (const float*)d_in[2];
    const float* b_in    = (const float*)d_in[3];
    const float* W_conv  = (const float*)d_in[4];
    const float* b_conv  = (const float*)d_in[5];
    const float* W_xp    = (const float*)d_in[6];
    const float* b_xp    = (const float*)d_in[7];
    const float* W_dt    = (const float*)d_in[8];
    const float* b_dt    = (const float*)d_in[9];
    const float* W_out   = (const float*)d_in[10];
    const float* b_out   = (const float*)d_in[11];
    const float* A_log   = (const float*)d_in[12];
    const float* D_param = (const float*)d_in[13];
    float* ws = (float*)d_ws;

    unsigned short* z_bf     = (unsigned short*)ws;               // 4.2M bf16
    unsigned short* u_cbf    = (unsigned short*)(ws + 2097152);
    unsigned short* delta_bf = (unsigned short*)(ws + 4194304);
    float* Bm     = ws + 6291456;
    float* Cm     = ws + 6815744;
    float* P      = ws + 7340032;
    float* Q      = ws + 8388608;
    float* Hinit  = ws + 9437184;
    unsigned short* Bp      = (unsigned short*)(ws + 10485760);
    unsigned short* Wxp_bf  = (unsigned short*)(ws + 10518528);
    unsigned short* Wout_bf = (unsigned short*)(ws + 10521600);
    unsigned short* Win_bf  = (unsigned short*)(ws + 10525696);
    float* out    = (float*)d_out;

    pack_all<<<376, 256, 0, stream>>>(W_in, w_norm, W_conv, W_xp, W_out,
                                      Win_bf, Bp, Wxp_bf, Wout_bf);

    void* args[] = {
        (void*)&x, (void*)&Win_bf, (void*)&b_in,
        (void*)&Bp, (void*)&b_conv,
        (void*)&Wxp_bf, (void*)&b_xp,
        (void*)&W_dt, (void*)&b_dt,
        (void*)&A_log, (void*)&D_param,
        (void*)&Wout_bf, (void*)&b_out,
        (void*)&z_bf,
        (void*)&P, (void*)&Q, (void*)&Hinit,
        (void*)&out,
    };
    hipError_t err = hipLaunchCooperativeKernel((const void*)mamba_coop,
                                                dim3(512), dim3(256),
                                                args, 0, stream);
    if (err != hipSuccess) {
        // Fallback: proven R14 multi-kernel path (bit-identical math).
        k123a_fused<<<512, 256, 0, stream>>>(x, Win_bf, b_in, Bp, b_conv,
                                             Wxp_bf, b_xp, W_dt, b_dt, A_log,
                                             z_bf, u_cbf, delta_bf, Bm, Cm, P, Q);
        k4b_carry<<<64, 256, 0, stream>>>(P, Q, Hinit);
        k4c5_fused<<<512, 256, 0, stream>>>(delta_bf, u_cbf, Bm, Cm, z_bf, A_log,
                                            D_param, Hinit, Wout_bf, b_out, x, out);
    }
}

// Round 17
// 174.279 us; speedup vs baseline: 1.7724x; 1.7724x over previous
//
#include <hip/hip_runtime.h>
#include <math.h>

#define D_MODEL 64
#define D_STATE 16
#define D_INNER 128
#define DT_RANK 4
#define BB 8
#define LL 4096
#define NTOK (BB*LL)      // 32768
#define EPSV 1e-6f
#define NCHUNK 64
#define LC (LL/NCHUNK)    // 64
#define PAD 136           // bf16 LDS row stride (shorts), 16B-aligned rows

typedef __attribute__((ext_vector_type(8))) short bf16x8;
typedef __attribute__((ext_vector_type(4))) float f32x4;

__device__ __forceinline__ float sig_(float v) { return 1.f / (1.f + __expf(-v)); }
__device__ __forceinline__ float softplus_(float v) {
    return (v > 20.f) ? v : __logf(1.f + __expf(v));
}
__device__ __forceinline__ unsigned short f2bf(float x) {
    unsigned int u = __float_as_uint(x);
    u += 0x7fff + ((u >> 16) & 1);      // RNE
    return (unsigned short)(u >> 16);
}
__device__ __forceinline__ float bf2f(unsigned short u) {
    return __uint_as_float(((unsigned int)u) << 16);
}
__device__ __forceinline__ unsigned int pack2bf(float a, float b) {
    return (unsigned int)f2bf(a) | ((unsigned int)f2bf(b) << 16);
}

// Pack all weights to bf16 in one kernel.
__global__ __launch_bounds__(256) void pack_all(
    const float* __restrict__ W_in, const float* __restrict__ w_norm,
    const float* __restrict__ W_conv, const float* __restrict__ W_xp,
    const float* __restrict__ W_out,
    unsigned short* __restrict__ Win_bf, unsigned short* __restrict__ Bp,
    unsigned short* __restrict__ Wxp_bf, unsigned short* __restrict__ Wout_bf)
{
    int i = blockIdx.x * 256 + threadIdx.x;
    if (i < 16384) {
        Win_bf[i] = f2bf(W_in[i] * w_norm[i & 63]);
    } else if (i < 81920) {
        int j = i - 16384;
        int kk = j >> 14, o = (j >> 7) & 127, c = j & 127;
        Bp[j] = f2bf(W_conv[o * 512 + c * 4 + kk]);
    } else if (i < 88064) {
        int j = i - 81920;
        Wxp_bf[j] = ((j >> 7) < 36) ? f2bf(W_xp[j]) : (unsigned short)0;
    } else if (i < 96256) {
        int j = i - 88064;
        Wout_bf[j] = f2bf(W_out[j]);
    }
}

// K1+K2+K3+K4a fused: RMSNorm+in_proj (3-row halo recompute), conv MFMA,
// x-proj MFMA, delta, chunk P/Q scan. blockIdx.x == b*NCHUNK + c.
// LDS 43,312 B (axs aliased into uls; upre aliased by dls) -> 3 blocks/CU.
__global__ __launch_bounds__(256) void k123a_fused(
    const float* __restrict__ x, const unsigned short* __restrict__ Win_bf,
    const float* __restrict__ b_in,
    const unsigned short* __restrict__ Bp, const float* __restrict__ b_conv,
    const unsigned short* __restrict__ Wxp_bf, const float* __restrict__ b_xp,
    const float* __restrict__ W_dt, const float* __restrict__ b_dt,
    const float* __restrict__ A_log,
    unsigned short* __restrict__ z_bf, unsigned short* __restrict__ u_cbf,
    unsigned short* __restrict__ delta_bf,
    float* __restrict__ Bm, float* __restrict__ Cm,
    float* __restrict__ P, float* __restrict__ Q)
{
    __shared__ unsigned char smem[43312];
    unsigned short* uls  = (unsigned short*)smem;             // [64][136] u_conv (phase>=1)
    unsigned short* axs  = uls;                               // [80][72] normed x (alias, dead after 0b)
    unsigned short* upre = (unsigned short*)(smem + 17408);   // [67][136] u_raw
    unsigned short* dls  = upre;                              // alias: delta (phase>=3)
    float* bls = (float*)(smem + 35632);                      // [64][16] Bm
    float (*dts)[4] = (float(*)[4])(smem + 39728);            // [64][4]
    float* Wd  = (float*)(smem + 40752);                      // [512]
    float* bds = (float*)(smem + 42800);                      // [128]

    int tid = threadIdx.x;
    if (tid < 128) *(float4*)&Wd[tid * 4] = *(const float4*)&W_dt[tid * 4];
    else if (tid < 160) *(float4*)&bds[(tid - 128) * 4] = *(const float4*)&b_dt[(tid - 128) * 4];
    int wave = tid >> 6, lane = tid & 63;
    int quad = lane >> 4, l16 = lane & 15;
    int tb = blockIdx.x * 64;
    int bbase = tb & ~4095;

    // ---- phase 0: RMSNorm rows tb-3 .. tb+63 -> axs ----
    #pragma unroll
    for (int p = 0; p < 2; ++p) {
        int lrow = p * 64 + (tid >> 2);
        if (lrow < 67) {
            int qt = tid & 3;
            int g = tb - 3 + lrow;
            float4 v[4];
            float ss = 0.f;
            if (g >= bbase) {
                #pragma unroll
                for (int j = 0; j < 4; ++j) {
                    v[j] = *(const float4*)&x[g * 64 + qt * 16 + j * 4];
                    ss += v[j].x*v[j].x + v[j].y*v[j].y + v[j].z*v[j].z + v[j].w*v[j].w;
                }
            } else {
                #pragma unroll
                for (int j = 0; j < 4; ++j) v[j] = (float4){0.f, 0.f, 0.f, 0.f};
            }
            ss += __shfl_xor(ss, 1, 64);
            ss += __shfl_xor(ss, 2, 64);
            float r = rsqrtf(ss * (1.f / 64.f) + EPSV);
            unsigned short tmp[16];
            #pragma unroll
            for (int j = 0; j < 4; ++j) {
                tmp[4*j+0] = f2bf(v[j].x * r); tmp[4*j+1] = f2bf(v[j].y * r);
                tmp[4*j+2] = f2bf(v[j].z * r); tmp[4*j+3] = f2bf(v[j].w * r);
            }
            *(bf16x8*)&axs[lrow * 72 + qt * 16]     = *(bf16x8*)&tmp[0];
            *(bf16x8*)&axs[lrow * 72 + qt * 16 + 8] = *(bf16x8*)&tmp[8];
        }
    }
    __syncthreads();
    // ---- phase 0b: in_proj MFMA (M=80/67 valid, N=256, K=64) ----
    #pragma unroll
    for (int mt = 0; mt < 5; ++mt) {
        bf16x8 a0 = *(const bf16x8*)&axs[(mt * 16 + l16) * 72 + quad * 8];
        bf16x8 a1 = *(const bf16x8*)&axs[(mt * 16 + l16) * 72 + 32 + quad * 8];
        f32x4 acc[4];
        #pragma unroll
        for (int nk = 0; nk < 4; ++nk) acc[nk] = (f32x4){0.f, 0.f, 0.f, 0.f};
        #pragma unroll
        for (int nk = 0; nk < 4; ++nk) {
            int nt = wave * 4 + nk;
            bf16x8 b0 = *(const bf16x8*)&Win_bf[(nt * 16 + l16) * 64 + quad * 8];
            bf16x8 b1 = *(const bf16x8*)&Win_bf[(nt * 16 + l16) * 64 + 32 + quad * 8];
            acc[nk] = __builtin_amdgcn_mfma_f32_16x16x32_bf16(a0, b0, acc[nk], 0, 0, 0);
            acc[nk] = __builtin_amdgcn_mfma_f32_16x16x32_bf16(a1, b1, acc[nk], 0, 0, 0);
        }
        #pragma unroll
        for (int nk = 0; nk < 4; ++nk) {
            int o = (wave * 4 + nk) * 16 + l16;
            float bo = b_in[o];
            #pragma unroll
            for (int r = 0; r < 4; ++r) {
                int lrow = mt * 16 + quad * 4 + r;
                if (lrow < 67) {
                    float v = acc[nk][r] + bo;
                    if (o < 128) {
                        upre[lrow * PAD + o] = f2bf(v);
                    } else if (lrow >= 3) {
                        float zv = v * sig_(v);
                        z_bf[(tb + lrow - 3) * 128 + (o - 128)] = f2bf(zv);
                    }
                }
            }
        }
    }
    __syncthreads();
    // ---- phase 1: conv MFMA (A from upre; uls writes overwrite dead axs) ----
    {
        f32x4 acc[8];
        #pragma unroll
        for (int og = 0; og < 8; ++og) acc[og] = (f32x4){0.f, 0.f, 0.f, 0.f};
        #pragma unroll
        for (int kk = 0; kk < 4; ++kk) {
            int lr = wave * 16 + l16 + kk;
            #pragma unroll
            for (int cs = 0; cs < 4; ++cs) {
                int kbase = cs * 32 + quad * 8;
                bf16x8 a = *(const bf16x8*)&upre[lr * PAD + kbase];
                #pragma unroll
                for (int og = 0; og < 8; ++og) {
                    bf16x8 b = *(const bf16x8*)&Bp[kk * 16384 + (og * 16 + l16) * 128 + kbase];
                    acc[og] = __builtin_amdgcn_mfma_f32_16x16x32_bf16(a, b, acc[og], 0, 0, 0);
                }
            }
        }
        #pragma unroll
        for (int og = 0; og < 8; ++og) {
            int o = og * 16 + l16;
            float bc = b_conv[o];
            #pragma unroll
            for (int r = 0; r < 4; ++r) {
                int tloc = wave * 16 + quad * 4 + r;
                float v = acc[og][r] + bc;
                unsigned short ub = f2bf(v * sig_(v));
                u_cbf[(tb + tloc) * 128 + o] = ub;
                uls[tloc * PAD + o] = ub;
            }
        }
    }
    __syncthreads();
    // ---- phase 2: x-proj (M=64, N=48 padded, K=128) ----
    {
        f32x4 xacc[3];
        #pragma unroll
        for (int nt = 0; nt < 3; ++nt) xacc[nt] = (f32x4){0.f, 0.f, 0.f, 0.f};
        #pragma unroll
        for (int cs = 0; cs < 4; ++cs) {
            int kbase = cs * 32 + quad * 8;
            bf16x8 a = *(const bf16x8*)&uls[(wave * 16 + l16) * PAD + kbase];
            #pragma unroll
            for (int nt = 0; nt < 3; ++nt) {
                bf16x8 b = *(const bf16x8*)&Wxp_bf[(nt * 16 + l16) * 128 + kbase];
                xacc[nt] = __builtin_amdgcn_mfma_f32_16x16x32_bf16(a, b, xacc[nt], 0, 0, 0);
            }
        }
        #pragma unroll
        for (int nt = 0; nt < 3; ++nt) {
            int j = nt * 16 + l16;
            float bx = (j < 36) ? b_xp[j] : 0.f;
            #pragma unroll
            for (int r = 0; r < 4; ++r) {
                int tloc = wave * 16 + quad * 4 + r;
                int t = tb + tloc;
                float val = xacc[nt][r] + bx;
                if (j < 4) {
                    dts[tloc][j] = val;
                } else if (j < 20) {
                    Bm[t * 16 + (j - 4)] = val;
                    bls[tloc * 16 + (j - 4)] = val;
                } else if (j < 36) {
                    Cm[t * 16 + (j - 20)] = val;
                }
            }
        }
    }
    __syncthreads();
    // ---- phase 3: delta = softplus(dt @ W_dt^T + b_dt), bf16 -> dls (alias) ----
    {
        int tokloc = tid >> 2, dgrp = tid & 3;
        float dt0 = dts[tokloc][0], dt1 = dts[tokloc][1],
              dt2 = dts[tokloc][2], dt3 = dts[tokloc][3];
        int g = tb + tokloc;
        #pragma unroll
        for (int d4 = 0; d4 < 8; ++d4) {
            int d = dgrp * 32 + d4 * 4;
            float4 w0 = *(const float4*)&Wd[(d + 0) * 4];
            float4 w1 = *(const float4*)&Wd[(d + 1) * 4];
            float4 w2 = *(const float4*)&Wd[(d + 2) * 4];
            float4 w3 = *(const float4*)&Wd[(d + 3) * 4];
            float4 bdv = *(const float4*)&bds[d];
            float4 r;
            r.x = softplus_(bdv.x + dt0*w0.x + dt1*w0.y + dt2*w0.z + dt3*w0.w);
            r.y = softplus_(bdv.y + dt0*w1.x + dt1*w1.y + dt2*w1.z + dt3*w1.w);
            r.z = softplus_(bdv.z + dt0*w2.x + dt1*w2.y + dt2*w2.z + dt3*w2.w);
            r.w = softplus_(bdv.w + dt0*w3.x + dt1*w3.y + dt2*w3.z + dt3*w3.w);
            uint2 pk; pk.x = pack2bf(r.x, r.y); pk.y = pack2bf(r.z, r.w);
            *(uint2*)&delta_bf[g * 128 + d] = pk;
            *(uint2*)&dls[tokloc * PAD + d] = pk;
        }
    }
    __syncthreads();
    // ---- phase 4: chunk P/Q scan (thread = d=tid>>1, n-oct=tid&1; 8 chains) ----
    {
        int d = tid >> 1;
        int nb = (tid & 1) * 8;
        float4 Av0 = *(const float4*)&A_log[d * 16 + nb];
        float4 Av1 = *(const float4*)&A_log[d * 16 + nb + 4];
        float A0 = -__expf(Av0.x), A1 = -__expf(Av0.y),
              A2 = -__expf(Av0.z), A3 = -__expf(Av0.w);
        float A4 = -__expf(Av1.x), A5 = -__expf(Av1.y),
              A6 = -__expf(Av1.z), A7 = -__expf(Av1.w);
        float P0=1.f,P1=1.f,P2=1.f,P3=1.f,P4=1.f,P5=1.f,P6=1.f,P7=1.f;
        float Q0=0.f,Q1=0.f,Q2=0.f,Q3=0.f,Q4=0.f,Q5=0.f,Q6=0.f,Q7=0.f;
        for (int t = 0; t < LC; ++t) {
            float dl = bf2f(dls[t * PAD + d]);
            float uu = bf2f(uls[t * PAD + d]);
            float4 bm0 = *(const float4*)&bls[t * 16 + nb];
            float4 bm1 = *(const float4*)&bls[t * 16 + nb + 4];
            float du = dl * uu;
            float a0 = __expf(dl * A0), a1 = __expf(dl * A1),
                  a2 = __expf(dl * A2), a3 = __expf(dl * A3);
            float a4 = __expf(dl * A4), a5 = __expf(dl * A5),
                  a6 = __expf(dl * A6), a7 = __expf(dl * A7);
            P0 *= a0; P1 *= a1; P2 *= a2; P3 *= a3;
            P4 *= a4; P5 *= a5; P6 *= a6; P7 *= a7;
            Q0 = a0 * Q0 + du * bm0.x; Q1 = a1 * Q1 + du * bm0.y;
            Q2 = a2 * Q2 + du * bm0.z; Q3 = a3 * Q3 + du * bm0.w;
            Q4 = a4 * Q4 + du * bm1.x; Q5 = a5 * Q5 + du * bm1.y;
            Q6 = a6 * Q6 + du * bm1.z; Q7 = a7 * Q7 + du * bm1.w;
        }
        int idx = blockIdx.x * 2048 + d * 16 + nb;
        *(float4*)&P[idx]     = (float4){P0, P1, P2, P3};
        *(float4*)&P[idx + 4] = (float4){P4, P5, P6, P7};
        *(float4*)&Q[idx]     = (float4){Q0, Q1, Q2, Q3};
        *(float4*)&Q[idx + 4] = (float4){Q4, Q5, Q6, Q7};
    }
}

// K4b: carry scan across chunks (8x unrolled: batch loads, then chain).
__global__ __launch_bounds__(256) void k4b_carry(
    const float* __restrict__ P, const float* __restrict__ Q, float* __restrict__ Hinit)
{
    int tid = blockIdx.x * 256 + threadIdx.x;  // 16384
    int b = tid >> 11, dn = tid & 2047;
    float carry = 0.f;
    for (int c0 = 0; c0 < NCHUNK; c0 += 8) {
        float p[8], q[8];
        #pragma unroll
        for (int j = 0; j < 8; ++j) {
            int idx = (b * NCHUNK + c0 + j) * 2048 + dn;
            p[j] = P[idx]; q[j] = Q[idx];
        }
        #pragma unroll
        for (int j = 0; j < 8; ++j) {
            int idx = (b * NCHUNK + c0 + j) * 2048 + dn;
            Hinit[idx] = carry;
            carry = p[j] * carry + q[j];
        }
    }
}

// K4c+K5 fused (57.4 KB LDS): full-d chunk replay -> y into yzls (z preloaded,
// same-thread overwrite) -> out-proj MFMA + residual.
__global__ __launch_bounds__(256) void k4c5_fused(
    const unsigned short* __restrict__ delta_bf, const unsigned short* __restrict__ u_cbf,
    const float* __restrict__ Bm, const float* __restrict__ Cm,
    const unsigned short* __restrict__ z_bf, const float* __restrict__ A_log,
    const float* __restrict__ D_param, const float* __restrict__ Hinit,
    const unsigned short* __restrict__ Wout_bf, const float* __restrict__ b_out,
    const float* __restrict__ x, float* __restrict__ out)
{
    __shared__ unsigned short dls[LC * 128];
    __shared__ unsigned short uls[LC * 128];
    __shared__ float bls[LC * 16];
    __shared__ float cls[LC * 16];
    __shared__ unsigned short yzls[LC * PAD];
    int bid = blockIdx.x;
    int tid = threadIdx.x, lane = tid & 63;
    int g0 = bid * 64;
    for (int i = tid; i < LC * 16; i += 256) {
        int row = i >> 4, q = i & 15;
        *(float4*)&dls[row * 128 + q * 8] =
            *(const float4*)&delta_bf[(g0 + row) * 128 + q * 8];
        *(float4*)&uls[row * 128 + q * 8] =
            *(const float4*)&u_cbf[(g0 + row) * 128 + q * 8];
        *(float4*)&yzls[row * PAD + q * 8] =
            *(const float4*)&z_bf[(g0 + row) * 128 + q * 8];
    }
    for (int i = tid; i < LC * 4; i += 256) {
        int row = i >> 2, q = i & 3;
        *(float4*)&bls[row * 16 + q * 4] = *(const float4*)&Bm[(g0 + row) * 16 + q * 4];
        *(float4*)&cls[row * 16 + q * 4] = *(const float4*)&Cm[(g0 + row) * 16 + q * 4];
    }
    int d = tid >> 1;
    int nb = (tid & 1) * 8;
    float4 Av0 = *(const float4*)&A_log[d * 16 + nb];
    float4 Av1 = *(const float4*)&A_log[d * 16 + nb + 4];
    float A0 = -__expf(Av0.x), A1 = -__expf(Av0.y), A2 = -__expf(Av0.z), A3 = -__expf(Av0.w);
    float A4 = -__expf(Av1.x), A5 = -__expf(Av1.y), A6 = -__expf(Av1.z), A7 = -__expf(Av1.w);
    int hbase = bid * 2048 + d * 16 + nb;
    float4 h0 = *(const float4*)&Hinit[hbase];
    float4 h1 = *(const float4*)&Hinit[hbase + 4];
    float Dp = D_param[d];
    __syncthreads();
    for (int t = 0; t < LC; ++t) {
        float dl = bf2f(dls[t * 128 + d]);
        float uu = bf2f(uls[t * 128 + d]);
        float4 bm0 = *(const float4*)&bls[t * 16 + nb];
        float4 bm1 = *(const float4*)&bls[t * 16 + nb + 4];
        float4 cm0 = *(const float4*)&cls[t * 16 + nb];
        float4 cm1 = *(const float4*)&cls[t * 16 + nb + 4];
        float du = dl * uu;
        float a0 = __expf(dl * A0), a1 = __expf(dl * A1),
              a2 = __expf(dl * A2), a3 = __expf(dl * A3);
        float a4 = __expf(dl * A4), a5 = __expf(dl * A5),
              a6 = __expf(dl * A6), a7 = __expf(dl * A7);
        h0.x = a0 * h0.x + du * bm0.x; h0.y = a1 * h0.y + du * bm0.y;
        h0.z = a2 * h0.z + du * bm0.z; h0.w = a3 * h0.w + du * bm0.w;
        h1.x = a4 * h1.x + du * bm1.x; h1.y = a5 * h1.y + du * bm1.y;
        h1.z = a6 * h1.z + du * bm1.z; h1.w = a7 * h1.w + du * bm1.w;
        float yv = h0.x * cm0.x + h0.y * cm0.y + h0.z * cm0.z + h0.w * cm0.w
                 + h1.x * cm1.x + h1.y * cm1.y + h1.z * cm1.z + h1.w * cm1.w;
        yv += __shfl_xor(yv, 1, 64);
        if ((tid & 1) == 0) {
            float y = yv + Dp * uu;
            y *= bf2f(yzls[t * PAD + d]);
            yzls[t * PAD + d] = f2bf(y);
        }
    }
    __syncthreads();
    int wave = tid >> 6;
    int quad = lane >> 4, l16 = lane & 15;
    f32x4 oacc[4];
    #pragma unroll
    for (int nt = 0; nt < 4; ++nt) oacc[nt] = (f32x4){0.f, 0.f, 0.f, 0.f};
    #pragma unroll
    for (int cs = 0; cs < 4; ++cs) {
        int kbase = cs * 32 + quad * 8;
        bf16x8 a = *(const bf16x8*)&yzls[(wave * 16 + l16) * PAD + kbase];
        #pragma unroll
        for (int nt = 0; nt < 4; ++nt) {
            bf16x8 bb = *(const bf16x8*)&Wout_bf[(nt * 16 + l16) * 128 + kbase];
            oacc[nt] = __builtin_amdgcn_mfma_f32_16x16x32_bf16(a, bb, oacc[nt], 0, 0, 0);
        }
    }
    #pragma unroll
    for (int nt = 0; nt < 4; ++nt) {
        int m = nt * 16 + l16;
        float bo = b_out[m];
        #pragma unroll
        for (int r = 0; r < 4; ++r) {
            int t = g0 + wave * 16 + quad * 4 + r;
            out[t * 64 + m] = oacc[nt][r] + bo + x[t * 64 + m];
        }
    }
}

extern "C" void kernel_launch(void* const* d_in, const int* in_sizes, int n_in,
                              void* d_out, int out_size, void* d_ws, size_t ws_size,
                              hipStream_t stream)
{
    const float* x       = (const float*)d_in[0];
    const float* w_norm  = (const float*)d_in[1];
    const float* W_in    = (const float*)d_in[2];
    const float* b_in    = (const float*)d_in[3];
    const float* W_conv  = (const float*)d_in[4];
    const float* b_conv  = (const float*)d_in[5];
    const float* W_xp    = (const float*)d_in[6];
    const float* b_xp    = (const float*)d_in[7];
    const float* W_dt    = (const float*)d_in[8];
    const float* b_dt    = (const float*)d_in[9];
    const float* W_out   = (const float*)d_in[10];
    const float* b_out   = (const float*)d_in[11];
    const float* A_log   = (const float*)d_in[12];
    const float* D_param = (const float*)d_in[13];
    float* ws = (float*)d_ws;

    unsigned short* z_bf     = (unsigned short*)ws;               // 4.2M bf16
    unsigned short* u_cbf    = (unsigned short*)(ws + 2097152);
    unsigned short* delta_bf = (unsigned short*)(ws + 4194304);
    float* Bm     = ws + 6291456;
    float* Cm     = ws + 6815744;
    float* P      = ws + 7340032;
    float* Q      = ws + 8388608;
    float* Hinit  = ws + 9437184;
    unsigned short* Bp      = (unsigned short*)(ws + 10485760);
    unsigned short* Wxp_bf  = (unsigned short*)(ws + 10518528);
    unsigned short* Wout_bf = (unsigned short*)(ws + 10521600);
    unsigned short* Win_bf  = (unsigned short*)(ws + 10525696);
    float* out    = (float*)d_out;

    pack_all<<<376, 256, 0, stream>>>(W_in, w_norm, W_conv, W_xp, W_out,
                                      Win_bf, Bp, Wxp_bf, Wout_bf);
    k123a_fused<<<512, 256, 0, stream>>>(x, Win_bf, b_in, Bp, b_conv,
                                         Wxp_bf, b_xp, W_dt, b_dt, A_log,
                                         z_bf, u_cbf, delta_bf, Bm, Cm, P, Q);
    k4b_carry<<<64, 256, 0, stream>>>(P, Q, Hinit);
    k4c5_fused<<<512, 256, 0, stream>>>(delta_bf, u_cbf, Bm, Cm, z_bf, A_log,
                                        D_param, Hinit, Wout_bf, b_out, x, out);
}